// Round 5
// baseline (256.262 us; speedup 1.0000x reference)
//
#include <hip/hip_runtime.h>
#include <hip/hip_bf16.h>
#include <stdint.h>

// LinearTimeSelfAttention MI355X, round 5:
//  - k1: ONE tile per block (2304 blocks), ONE barrier per block lifetime.
//    Per-head wave mapping (phase B reads wave-private LDS); phase A/B split
//    into two 32-n halves reusing a small wave-private Ps (in-wave ordering,
//    no barrier). LDS 37.9 KB -> 4 blocks/CU; launch_bounds(256,3).
//  - k0: pre-convert W_kv to bf16 frag-ready layout (64 KB, L2-resident);
//    per-block W init = 16 coalesced dwordx4 per wave.
// Folding unchanged: y = Bm@x + cvec; Bm = A@W_q; A = (W_out ctx)/S;
// ctx = sum_n e^k v^T; S = sum_n e^k.

#define NPOS 147456      // 384*384
#define NTILES 2304      // NPOS / 64
#define NB1 2304         // one tile per block

typedef __attribute__((ext_vector_type(8))) short short8;
typedef __attribute__((ext_vector_type(4))) float floatx4;

__device__ __forceinline__ uint16_t f2bf(float f) {
    uint32_t u = __float_as_uint(f);
    return (uint16_t)((u + 0x7fffu + ((u >> 16) & 1u)) >> 16);   // RNE
}
__device__ __forceinline__ uint32_t pack2(float a, float b) {
#if __has_builtin(__builtin_amdgcn_cvt_pk_bf16_f32)
    auto r = __builtin_amdgcn_cvt_pk_bf16_f32(a, b);
    uint32_t u; __builtin_memcpy(&u, &r, sizeof(u));
    return u;
#else
    return (uint32_t)f2bf(a) | ((uint32_t)f2bf(b) << 16);
#endif
}

// strides in 32-bit LDS words (must be multiples of 4 for aligned b128 reads)
#define XS_STRIDE 68     // 136 bf16 per n-row (128 ch + 8 pad)
#define PS_STRIDE 20     // 40 bf16 per kvrow (32 n + 8 pad)

__device__ __forceinline__ void xt_load(const float* __restrict__ xb, float* pf) {
    #pragma unroll
    for (int i = 0; i < 32; ++i) pf[i] = xb[(size_t)i * NPOS];
}
__device__ __forceinline__ void xt_store(uint32_t* Xsbuf, const float* pf, int lane, int c0) {
    #pragma unroll
    for (int i = 0; i < 8; ++i) {
        uint2 w;
        w.x = pack2(pf[i * 4 + 0], pf[i * 4 + 1]);
        w.y = pack2(pf[i * 4 + 2], pf[i * 4 + 3]);
        *(uint2*)&Xsbuf[lane * XS_STRIDE + (c0 + i * 4) / 2] = w;
    }
}

// ---------------- K0: W_kv fp32 -> bf16 packed, frag-ready layout ----------------
// Wp[f*256 + l*4 + w], f=(head*4+kt)*4+ks, l=quad*16+m:
//   = pack2(W[row][k], W[row][k+1]), row=krow/vrow(head,kt)+m, k=ks*32+quad*8+2w
__global__ void k0_wconv(const float* __restrict__ w_qkv, uint32_t* __restrict__ Wp)
{
    const int idx = blockIdx.x * 256 + threadIdx.x;   // 16384
    const int f = idx >> 8, l = (idx >> 2) & 63, w = idx & 3;
    const int head = f >> 4, kt = (f >> 2) & 3, ks = f & 3;
    const int m = l & 15, quad = l >> 4;
    const int row = (kt < 2 ? 128 + head * 32 + kt * 16
                            : 256 + head * 32 + (kt - 2) * 16) + m;
    const int k = ks * 32 + quad * 8 + 2 * w;
    Wp[idx] = pack2(w_qkv[row * 128 + k], w_qkv[row * 128 + k + 1]);
}

// ---------------- K1: projections + exp + partial context ----------------
__global__ __launch_bounds__(256, 3) void k1_ctx(
    const float* __restrict__ x, const uint32_t* __restrict__ Wp,
    const float* __restrict__ b_qkv, float* __restrict__ cpart, int nb1)
{
    __shared__ uint32_t Xs[64 * XS_STRIDE];          // 17.4 KB
    __shared__ uint32_t Ps[256 * PS_STRIDE];         // 20.5 KB, 4 wave-private regions

    const int t = threadIdx.x;
    const int lane = t & 63;
    const int wavu = __builtin_amdgcn_readfirstlane(t >> 6);
    const int m = lane & 15, quad = lane >> 4;
    const int c0 = wavu * 32;
    uint32_t* const Psw = &Ps[wavu * 64 * PS_STRIDE];

    // W fragments: 16 coalesced dwordx4 from frag-ready Wp
    short8 wfr[4][4];
    float biasv[4];
    #pragma unroll
    for (int kt = 0; kt < 4; ++kt) {
        biasv[kt] = b_qkv[(kt < 2 ? 128 + wavu * 32 + kt * 16
                                  : 256 + wavu * 32 + (kt - 2) * 16) + m];
        #pragma unroll
        for (int ks = 0; ks < 4; ++ks) {
            uint4 u = *(const uint4*)&Wp[(((wavu * 4 + kt) * 4 + ks) << 8) + lane * 4];
            short8 w; __builtin_memcpy(&w, &u, sizeof(w));
            wfr[kt][ks] = w;
        }
    }

    floatx4 acc2[4];
    #pragma unroll
    for (int i = 0; i < 4; ++i) acc2[i] = (floatx4){0.f, 0.f, 0.f, 0.f};
    float sacc[2] = {0.f, 0.f};

    const float* xw = x + (size_t)c0 * NPOS + lane;

    for (int tile = blockIdx.x; tile < NTILES; tile += nb1) {
        float pf[32];
        xt_load(xw + tile * 64, pf);
        xt_store(Xs, pf, lane, c0);
        __syncthreads();                             // the only barrier per block

        #pragma unroll
        for (int half = 0; half < 2; ++half) {
            // phase A for n-half: P^T[n][local kvrow], local rows 0-31 k, 32-63 v
            #pragma unroll
            for (int ntl = 0; ntl < 2; ++ntl) {
                const int nt = half * 2 + ntl;
                short8 afr[4];
                #pragma unroll
                for (int ks = 0; ks < 4; ++ks)
                    afr[ks] = *(const short8*)&Xs[(nt * 16 + m) * XS_STRIDE + ks * 16 + quad * 4];
                floatx4 pa[4];
                #pragma unroll
                for (int kt = 0; kt < 4; ++kt) pa[kt] = (floatx4){0.f, 0.f, 0.f, 0.f};
                #pragma unroll
                for (int ks = 0; ks < 4; ++ks)
                    #pragma unroll
                    for (int kt = 0; kt < 4; ++kt)
                        pa[kt] = __builtin_amdgcn_mfma_f32_16x16x32_bf16(afr[ks], wfr[kt][ks], pa[kt], 0, 0, 0);
                #pragma unroll
                for (int kt = 0; kt < 4; ++kt) {
                    float v0 = pa[kt][0] + biasv[kt];
                    float v1 = pa[kt][1] + biasv[kt];
                    float v2 = pa[kt][2] + biasv[kt];
                    float v3 = pa[kt][3] + biasv[kt];
                    if (kt < 2) {                    // k rows of this head
                        v0 = __expf(v0); v1 = __expf(v1);
                        v2 = __expf(v2); v3 = __expf(v3);
                        sacc[kt] += (v0 + v1) + (v2 + v3);
                    }
                    uint2 w;
                    w.x = pack2(v0, v1);
                    w.y = pack2(v2, v3);
                    *(uint2*)&Psw[(kt * 16 + m) * PS_STRIDE + ntl * 8 + quad * 2] = w;
                }
            }
            // phase B for this half: ctx += Ek V^T (wave-private Ps, no barrier)
            short8 ea[2], vb[2];
            #pragma unroll
            for (int dt = 0; dt < 2; ++dt)
                ea[dt] = *(const short8*)&Psw[(dt * 16 + m) * PS_STRIDE + quad * 4];
            #pragma unroll
            for (int et = 0; et < 2; ++et)
                vb[et] = *(const short8*)&Psw[(32 + et * 16 + m) * PS_STRIDE + quad * 4];
            #pragma unroll
            for (int dt = 0; dt < 2; ++dt)
                #pragma unroll
                for (int et = 0; et < 2; ++et)
                    acc2[dt * 2 + et] = __builtin_amdgcn_mfma_f32_16x16x32_bf16(ea[dt], vb[et], acc2[dt * 2 + et], 0, 0, 0);
        }
        if (tile + nb1 < NTILES) __syncthreads();    // only in ws-fallback mode
    }

    // partials: [0..4095] ctx (h*1024 + d*32 + e), [4096..4223] S
    float* __restrict__ dst = cpart + (size_t)blockIdx.x * 4224;
    #pragma unroll
    for (int dt = 0; dt < 2; ++dt)
        #pragma unroll
        for (int et = 0; et < 2; ++et)
            #pragma unroll
            for (int r = 0; r < 4; ++r) {
                const int d = dt * 16 + quad * 4 + r, e = et * 16 + m;
                dst[wavu * 1024 + d * 32 + e] = acc2[dt * 2 + et][r];
            }
    #pragma unroll
    for (int kt = 0; kt < 2; ++kt) {
        float s = sacc[kt];
        s += __shfl_down(s, 32, 64);
        s += __shfl_down(s, 16, 64);
        if (lane < 16) dst[4096 + wavu * 32 + kt * 16 + lane] = s;
    }
}

// ---------------- K2a: reduce nb1 partials -> 8 partials ----------------
__global__ void k2a(const float* __restrict__ cpart, float* __restrict__ ctxP, int nb1)
{
    const int u = blockIdx.x * 256 + threadIdx.x;
    if (u >= 4224 * 8) return;
    const int j = u % 4224, p = u / 4224;
    float s = 0.f;
    for (int b = p; b < nb1; b += 8) s += cpart[(size_t)b * 4224 + j];
    ctxP[p * 4224 + j] = s;
}

// ---------------- K2bc: per-o A row -> bf16 Bm row + cvec ----------------
__global__ __launch_bounds__(128) void k2bc(
    const float* __restrict__ ctxP, const float* __restrict__ w_out,
    const float* __restrict__ w_qkv, const float* __restrict__ b_qkv,
    const float* __restrict__ b_out, uint32_t* __restrict__ Bmb, float* __restrict__ cvec)
{
    __shared__ float ctx33[128 * 33];
    __shared__ float Ss[128];
    __shared__ float Arow[128];
    __shared__ float row[128];
    __shared__ float red[128];
    const int o = blockIdx.x, t = threadIdx.x;
    for (int j = t; j < 4224; j += 128) {
        float s = 0.f;
        #pragma unroll
        for (int p = 0; p < 8; ++p) s += ctxP[p * 4224 + j];
        if (j < 4096) ctx33[(j >> 5) * 33 + (j & 31)] = s;
        else          Ss[j - 4096] = s;
    }
    __syncthreads();
    {   // A[o][hd], hd = t
        const int h = t >> 5;
        float s = 0.f;
        #pragma unroll
        for (int e = 0; e < 32; ++e)
            s = fmaf(w_out[o * 128 + h * 32 + e], ctx33[t * 33 + e], s);
        Arow[t] = s / Ss[t];
    }
    __syncthreads();
    {   // Bm[o][c], c = t
        float s = 0.f;
        #pragma unroll 16
        for (int hd = 0; hd < 128; ++hd)
            s = fmaf(Arow[hd], w_qkv[hd * 128 + t], s);
        row[t] = s;
    }
    red[t] = Arow[t] * b_qkv[t];
    __syncthreads();
    if (t < 64) Bmb[o * 64 + t] = pack2(row[2 * t], row[2 * t + 1]);
    if (t == 0) {
        float cs = b_out[o];
        #pragma unroll 8
        for (int i = 0; i < 128; ++i) cs += red[i];
        cvec[o] = cs;
    }
}

// ---------------- K3: y = Bm @ x + cvec ----------------
__global__ __launch_bounds__(256) void k3(
    const float* __restrict__ x, const uint32_t* __restrict__ Bmb,
    const float* __restrict__ cvec, float* __restrict__ y)
{
    __shared__ uint32_t Xs[64 * XS_STRIDE];
    const int t = threadIdx.x, lane = t & 63;
    const int wavu = __builtin_amdgcn_readfirstlane(t >> 6);
    const int m = lane & 15, quad = lane >> 4;
    const int n0 = blockIdx.x * 64;
    const int c0 = wavu * 32;

    float pf[32];
    xt_load(x + (size_t)c0 * NPOS + n0 + lane, pf);

    short8 bfr[2][4];
    float cv[2];
    #pragma unroll
    for (int ot = 0; ot < 2; ++ot) {
        const int o = (wavu * 2 + ot) * 16 + m;
        cv[ot] = cvec[o];
        #pragma unroll
        for (int ks = 0; ks < 4; ++ks) {
            uint4 u = *(const uint4*)&Bmb[o * 64 + ks * 16 + quad * 4];
            short8 w; __builtin_memcpy(&w, &u, sizeof(w));
            bfr[ot][ks] = w;
        }
    }
    xt_store(Xs, pf, lane, c0);
    __syncthreads();

    floatx4 acc[2][4];
    #pragma unroll
    for (int ot = 0; ot < 2; ++ot)
        #pragma unroll
        for (int nt = 0; nt < 4; ++nt) acc[ot][nt] = (floatx4){0.f, 0.f, 0.f, 0.f};
    #pragma unroll
    for (int nt = 0; nt < 4; ++nt) {
        short8 afr[4];
        #pragma unroll
        for (int ks = 0; ks < 4; ++ks)
            afr[ks] = *(const short8*)&Xs[(nt * 16 + m) * XS_STRIDE + ks * 16 + quad * 4];
        #pragma unroll
        for (int ks = 0; ks < 4; ++ks)
            #pragma unroll
            for (int ot = 0; ot < 2; ++ot)
                acc[ot][nt] = __builtin_amdgcn_mfma_f32_16x16x32_bf16(afr[ks], bfr[ot][ks], acc[ot][nt], 0, 0, 0);
    }
    #pragma unroll
    for (int ot = 0; ot < 2; ++ot) {
        const int o = (wavu * 2 + ot) * 16 + m;
        #pragma unroll
        for (int nt = 0; nt < 4; ++nt) {
            floatx4 v = acc[ot][nt];
            v.x += cv[ot]; v.y += cv[ot]; v.z += cv[ot]; v.w += cv[ot];
            *(floatx4*)(y + (size_t)o * NPOS + n0 + nt * 16 + quad * 4) = v;
        }
    }
}

extern "C" void kernel_launch(void* const* d_in, const int* in_sizes, int n_in,
                              void* d_out, int out_size, void* d_ws, size_t ws_size,
                              hipStream_t stream)
{
    const float* x     = (const float*)d_in[0];
    const float* w_qkv = (const float*)d_in[1];
    const float* b_qkv = (const float*)d_in[2];
    const float* w_out = (const float*)d_in[3];
    const float* b_out = (const float*)d_in[4];
    float* y = (float*)d_out;

    // ws: Wp[16384 u32] | ctxP[8*4224 f32] | Bmb[8192 u32] | cvec[128 f32] | cpart[nb1][4224]
    const size_t head = (size_t)(16384 + 8 * 4224 + 8192 + 128) * 4;
    int nb1 = NB1;
    if (ws_size < head + (size_t)nb1 * 16896) {
        long cap = ((long)ws_size - (long)head) / 16896;
        nb1 = (int)cap;
        if (nb1 < 1) nb1 = 1;
        if (nb1 > NB1) nb1 = NB1;
    }
    char* wsb = (char*)d_ws;
    uint32_t* Wp   = (uint32_t*)wsb;
    float* ctxP    = (float*)(Wp + 16384);
    uint32_t* Bmb  = (uint32_t*)(ctxP + 8 * 4224);
    float* cvec    = (float*)(Bmb + 8192);
    float* cpart   = cvec + 128;

    hipLaunchKernelGGL(k0_wconv, dim3(64), dim3(256), 0, stream, w_qkv, Wp);
    hipLaunchKernelGGL(k1_ctx, dim3(nb1), dim3(256), 0, stream, x, Wp, b_qkv, cpart, nb1);
    hipLaunchKernelGGL(k2a, dim3(132), dim3(256), 0, stream, cpart, ctxP, nb1);
    hipLaunchKernelGGL(k2bc, dim3(128), dim3(128), 0, stream, ctxP, w_out, w_qkv, b_qkv, b_out, Bmb, cvec);
    hipLaunchKernelGGL(k3, dim3(NTILES), dim3(256), 0, stream, x, Bmb, cvec, y);
}